// Round 10
// baseline (363.864 us; speedup 1.0000x reference)
//
#include <hip/hip_runtime.h>
#include <hip/hip_bf16.h>

// GPS model forward. Dense GEMMs split-bf16 MFMA (~fp32 accurate); attention
// core single-bf16 MFMA (64-q tile, 16 kv-splits, bf16 partial stores). GCN
// via CSR gather. qkv prep fused into dual GEMM epilogue; out-proj GEMM merges
// kv-split partials + 1/l in A-load; BN applies merged; pooling fused.
// N=4096, IN=16, C=128, H=2 (dh=64), E=131072, G=64.

constexpr int N_  = 4096;
constexpr int IN_ = 16;
constexpr int C_  = 128;
constexpr int E_  = 131072;
constexpr int G_  = 64;
constexpr float EPSV = 1e-5f;
constexpr int SP_ = 16;                  // kv-splits in flash (64-q tile, low VGPR)

typedef unsigned short u16;
typedef __attribute__((ext_vector_type(8))) short bf16x8;
typedef __attribute__((ext_vector_type(8))) unsigned short u16x8;
typedef __attribute__((ext_vector_type(4))) float f32x4;

__device__ inline u16 f2bf(float f) {   // HW cvt (RNE on gfx950)
  union { __hip_bfloat16 b; u16 u; } v;
  v.b = __float2bfloat16(f);
  return v.u;
}
__device__ inline float bf2f(u16 s) {
  union { unsigned u; float f; } v; v.u = ((unsigned)s) << 16;
  return v.f;
}

// ---------------- projection: h = x @ projW + projb ----------------
__global__ __launch_bounds__(256) void proj_k(const float* __restrict__ x,
                                              const float* __restrict__ W,
                                              const float* __restrict__ b,
                                              float* __restrict__ h) {
  int idx = blockIdx.x * 256 + threadIdx.x;   // N*C threads
  int n = idx >> 7, c = idx & 127;
  float acc = b[c];
#pragma unroll
  for (int k = 0; k < IN_; ++k) acc = fmaf(x[n * IN_ + k], W[k * C_ + c], acc);
  h[idx] = acc;
}

// ---------------- CSR build ----------------
__global__ __launch_bounds__(256) void count_k(const int* __restrict__ ei,
                                               int* __restrict__ cnt) {
  int e = blockIdx.x * 256 + threadIdx.x;
  atomicAdd(&cnt[ei[E_ + e]], 1);          // dst = ei[1][e]
}
__global__ __launch_bounds__(256) void scan_k(const int* __restrict__ cnt,
                                              int* __restrict__ rowptr,
                                              int* __restrict__ cursor,
                                              float* __restrict__ dinv) {
  __shared__ int part[256];
  const int t = threadIdx.x;
  int v[16], s = 0;
#pragma unroll
  for (int i = 0; i < 16; ++i) { v[i] = cnt[t * 16 + i]; s += v[i]; }
  part[t] = s;
  __syncthreads();
  if (t == 0) {
    int run = 0;
    for (int i = 0; i < 256; ++i) { int x = part[i]; part[i] = run; run += x; }
  }
  __syncthreads();
  int off = part[t];
#pragma unroll
  for (int i = 0; i < 16; ++i) {
    int n = t * 16 + i;
    rowptr[n] = off; cursor[n] = off;
    dinv[n] = rsqrtf((float)v[i] + 1.0f);  // +1 self loop
    off += v[i];
  }
  if (t == 0) rowptr[N_] = E_;
}
__global__ __launch_bounds__(256) void fill_k(const int* __restrict__ ei,
                                              int* __restrict__ cursor,
                                              int* __restrict__ csr) {
  int e = blockIdx.x * 256 + threadIdx.x;
  int d = ei[E_ + e];
  int slot = atomicAdd(&cursor[d], 1);
  csr[slot] = ei[e];                       // src
}

// ---------------- weight prep: fp32 -> split-bf16 [col][k] ----------------
// Per-layer u16 offsets: gcn@0 + qkv@16384 (contiguous 512x128), out@65536,
// w1@81920, w2@114688; layer stride 147456.
__global__ __launch_bounds__(256) void wprep_k(const float* __restrict__ gcnW,
                                               const float* __restrict__ qkvW,
                                               const float* __restrict__ outW,
                                               const float* __restrict__ w1,
                                               const float* __restrict__ w2,
                                               u16* __restrict__ Wh,
                                               u16* __restrict__ Wl) {
  int bx = blockIdx.x;                     // 288 blocks (2 layers x 144)
  int l = bx / 144, b = bx % 144;
  const float* src; int dstOff, K, M, trans;
  if (b < 16)       { src = gcnW + l * 16384; dstOff = 0;      K = 128; M = 128; trans = 0; }
  else if (b < 64)  { src = qkvW + l * 49152; dstOff = 16384;  K = 128; M = 0;   trans = 1; b -= 16; }
  else if (b < 80)  { src = outW + l * 16384; dstOff = 65536;  K = 128; M = 0;   trans = 1; b -= 64; }
  else if (b < 112) { src = w1 + l * 32768;   dstOff = 81920;  K = 128; M = 256; trans = 0; b -= 80; }
  else              { src = w2 + l * 32768;   dstOff = 114688; K = 256; M = 128; trans = 0; b -= 112; }
  dstOff += l * 147456;
  int d = b * 1024 + threadIdx.x * 4;
  float v[4];
  if (trans) {
    const float4 f = *(const float4*)&src[d];
    v[0] = f.x; v[1] = f.y; v[2] = f.z; v[3] = f.w;
  } else {
    int ks = (K == 256) ? 8 : 7;
    int n = d >> ks, k = d & (K - 1);
#pragma unroll
    for (int j = 0; j < 4; ++j) v[j] = src[(size_t)(k + j) * M + n];
  }
  ushort4 hv, lv;
  u16* hp = (u16*)&hv; u16* lp = (u16*)&lv;
#pragma unroll
  for (int j = 0; j < 4; ++j) {
    u16 hh = f2bf(v[j]); hp[j] = hh; lp[j] = f2bf(v[j] - bf2f(hh));
  }
  *(ushort4*)&Wh[dstOff + d] = hv;
  *(ushort4*)&Wl[dstOff + d] = lv;
}

// ---------------- dual GEMM + qkv prep epilogue ----------------
// grid (8, 64). Col-blocks: 0-1 -> t0 (gcn hw, fp32); 2-3 -> Qg bf16 (scaled,
// +bias); 4-5 -> Kg bf16 (+bias); 6-7 -> Vtg bf16 transposed (+bias).
__global__ __launch_bounds__(256) void mgemm_dual_k(const float* __restrict__ A,
                                                    const u16* __restrict__ Bh,
                                                    const u16* __restrict__ Bl,
                                                    const float* __restrict__ qkvB,
                                                    float* __restrict__ t0,
                                                    u16* __restrict__ Qg,
                                                    u16* __restrict__ Kg,
                                                    u16* __restrict__ Vtg) {
  constexpr int LD = 72, K = 128;
  __shared__ u16 Ah[64 * LD], Al[64 * LD], Bsh[64 * LD], Bsl[64 * LD];
  const int tid = threadIdx.x;
  const int row0 = blockIdx.y * 64, col0 = blockIdx.x * 64;
  const int wv = tid >> 6, ln = tid & 63, quad = ln >> 4, c = ln & 15;
  f32x4 acc[4];
#pragma unroll
  for (int i = 0; i < 4; ++i) acc[i] = (f32x4){0.f, 0.f, 0.f, 0.f};

  for (int kt = 0; kt < K; kt += 64) {
    __syncthreads();
#pragma unroll
    for (int i = 0; i < 2; ++i) {
      int ch = tid + i * 256, r = ch >> 3, part = ch & 7;
      const float4 f0 = *(const float4*)&A[(size_t)(row0 + r) * K + kt + part * 8];
      const float4 f1 = *(const float4*)&A[(size_t)(row0 + r) * K + kt + part * 8 + 4];
      float fv[8] = {f0.x, f0.y, f0.z, f0.w, f1.x, f1.y, f1.z, f1.w};
      __attribute__((aligned(16))) u16 hb[8], lb[8];
#pragma unroll
      for (int j = 0; j < 8; ++j) {
        u16 hh = f2bf(fv[j]); hb[j] = hh; lb[j] = f2bf(fv[j] - bf2f(hh));
      }
      *(u16x8*)&Ah[r * LD + part * 8] = *(u16x8*)hb;
      *(u16x8*)&Al[r * LD + part * 8] = *(u16x8*)lb;
      size_t bo = (size_t)(col0 + r) * K + kt + part * 8;
      *(u16x8*)&Bsh[r * LD + part * 8] = *(const u16x8*)&Bh[bo];
      *(u16x8*)&Bsl[r * LD + part * 8] = *(const u16x8*)&Bl[bo];
    }
    __syncthreads();
#pragma unroll
    for (int kq = 0; kq < 2; ++kq) {
      bf16x8 ah = *(const bf16x8*)&Ah[(wv * 16 + c) * LD + kq * 32 + quad * 8];
      bf16x8 al = *(const bf16x8*)&Al[(wv * 16 + c) * LD + kq * 32 + quad * 8];
#pragma unroll
      for (int cb = 0; cb < 4; ++cb) {
        bf16x8 bh = *(const bf16x8*)&Bsh[(cb * 16 + c) * LD + kq * 32 + quad * 8];
        bf16x8 bl = *(const bf16x8*)&Bsl[(cb * 16 + c) * LD + kq * 32 + quad * 8];
        acc[cb] = __builtin_amdgcn_mfma_f32_16x16x32_bf16(al, bh, acc[cb], 0, 0, 0);
        acc[cb] = __builtin_amdgcn_mfma_f32_16x16x32_bf16(ah, bl, acc[cb], 0, 0, 0);
        acc[cb] = __builtin_amdgcn_mfma_f32_16x16x32_bf16(ah, bh, acc[cb], 0, 0, 0);
      }
    }
  }

  const int cls = blockIdx.x;            // block-uniform
  if (cls < 2) {                         // gcn hw -> t0, fp32, no bias
#pragma unroll
    for (int cb = 0; cb < 4; ++cb)
#pragma unroll
      for (int r = 0; r < 4; ++r) {
        int rr = row0 + wv * 16 + quad * 4 + r;
        t0[(size_t)rr * 128 + col0 + cb * 16 + c] = acc[cb][r];
      }
  } else if (cls < 6) {                  // Q or K -> bf16 [h][n][64]
    const int isQ = cls < 4, h = cls & 1;
    const float sc = isQ ? 0.125f : 1.0f;
    u16* dst = isQ ? Qg : Kg;
#pragma unroll
    for (int cb = 0; cb < 4; ++cb) {
      int d = cb * 16 + c;
      float qb = qkvB[col0 - 128 + d];
#pragma unroll
      for (int r = 0; r < 4; ++r) {
        int rr = row0 + wv * 16 + quad * 4 + r;
        dst[((size_t)(h * N_ + rr)) * 64 + d] = f2bf((acc[cb][r] + qb) * sc);
      }
    }
  } else {                               // V -> bf16 transposed [h][64][n]
    const int h = cls & 1;
    u16* vtile = Ah;                     // reuse (64 x 72)
    __syncthreads();                     // all MFMA LDS reads done
#pragma unroll
    for (int cb = 0; cb < 4; ++cb) {
      int d = cb * 16 + c;
      float vb = qkvB[col0 - 128 + d];
#pragma unroll
      for (int r = 0; r < 4; ++r)
        vtile[(wv * 16 + quad * 4 + r) * LD + d] = f2bf(acc[cb][r] + vb);
    }
    __syncthreads();
    int d = tid >> 2, j = tid & 3;
    __attribute__((aligned(16))) u16 buf[16];
#pragma unroll
    for (int m = 0; m < 16; ++m) buf[m] = vtile[(j * 16 + m) * LD + d];
    size_t o = ((size_t)(h * 64 + d)) * N_ + row0 + j * 16;
    *(u16x8*)&Vtg[o]     = *(u16x8*)&buf[0];
    *(u16x8*)&Vtg[o + 8] = *(u16x8*)&buf[8];
  }
}

// ---------------- generic MFMA GEMM with fused epilogue ----------------
// C = A @ B^T + bias [+resid] [,relu]; optional column stats into sums.
__global__ __launch_bounds__(256) void mgemm_k(const float* __restrict__ A,
                                               const u16* __restrict__ Bh,
                                               const u16* __restrict__ Bl,
                                               const float* __restrict__ bias,
                                               float* __restrict__ Cout,
                                               int K, int Ncols, int relu,
                                               const float* __restrict__ resid,
                                               float* __restrict__ sums) {
  constexpr int LD = 72;
  __shared__ u16 Ah[64 * LD], Al[64 * LD], Bsh[64 * LD], Bsl[64 * LD];
  const int tid = threadIdx.x;
  const int row0 = blockIdx.y * 64, col0 = blockIdx.x * 64;
  const int wv = tid >> 6, ln = tid & 63, quad = ln >> 4, c = ln & 15;
  f32x4 acc[4];
#pragma unroll
  for (int i = 0; i < 4; ++i) acc[i] = (f32x4){0.f, 0.f, 0.f, 0.f};

  for (int kt = 0; kt < K; kt += 64) {
    __syncthreads();
#pragma unroll
    for (int i = 0; i < 2; ++i) {
      int ch = tid + i * 256, r = ch >> 3, part = ch & 7;
      const float4 f0 = *(const float4*)&A[(size_t)(row0 + r) * K + kt + part * 8];
      const float4 f1 = *(const float4*)&A[(size_t)(row0 + r) * K + kt + part * 8 + 4];
      float fv[8] = {f0.x, f0.y, f0.z, f0.w, f1.x, f1.y, f1.z, f1.w};
      __attribute__((aligned(16))) u16 hb[8], lb[8];
#pragma unroll
      for (int j = 0; j < 8; ++j) {
        u16 hh = f2bf(fv[j]); hb[j] = hh; lb[j] = f2bf(fv[j] - bf2f(hh));
      }
      *(u16x8*)&Ah[r * LD + part * 8] = *(u16x8*)hb;
      *(u16x8*)&Al[r * LD + part * 8] = *(u16x8*)lb;
      size_t bo = (size_t)(col0 + r) * K + kt + part * 8;
      *(u16x8*)&Bsh[r * LD + part * 8] = *(const u16x8*)&Bh[bo];
      *(u16x8*)&Bsl[r * LD + part * 8] = *(const u16x8*)&Bl[bo];
    }
    __syncthreads();
#pragma unroll
    for (int kq = 0; kq < 2; ++kq) {
      bf16x8 ah = *(const bf16x8*)&Ah[(wv * 16 + c) * LD + kq * 32 + quad * 8];
      bf16x8 al = *(const bf16x8*)&Al[(wv * 16 + c) * LD + kq * 32 + quad * 8];
#pragma unroll
      for (int cb = 0; cb < 4; ++cb) {
        bf16x8 bh = *(const bf16x8*)&Bsh[(cb * 16 + c) * LD + kq * 32 + quad * 8];
        bf16x8 bl = *(const bf16x8*)&Bsl[(cb * 16 + c) * LD + kq * 32 + quad * 8];
        acc[cb] = __builtin_amdgcn_mfma_f32_16x16x32_bf16(al, bh, acc[cb], 0, 0, 0);
        acc[cb] = __builtin_amdgcn_mfma_f32_16x16x32_bf16(ah, bl, acc[cb], 0, 0, 0);
        acc[cb] = __builtin_amdgcn_mfma_f32_16x16x32_bf16(ah, bh, acc[cb], 0, 0, 0);
      }
    }
  }
#pragma unroll
  for (int cb = 0; cb < 4; ++cb) {
    float s = 0.0f, s2 = 0.0f;
#pragma unroll
    for (int r = 0; r < 4; ++r) {
      int rr = row0 + wv * 16 + quad * 4 + r;
      int cc = col0 + cb * 16 + c;
      float o = acc[cb][r] + (bias ? bias[cc] : 0.0f);
      if (resid) o += resid[(size_t)rr * Ncols + cc];
      if (relu) o = fmaxf(o, 0.0f);
      Cout[(size_t)rr * Ncols + cc] = o;
      s += o; s2 = fmaf(o, o, s2);
    }
    if (sums) {
      s  += __shfl_xor(s, 16);  s  += __shfl_xor(s, 32);
      s2 += __shfl_xor(s2, 16); s2 += __shfl_xor(s2, 32);
      if (quad == 0) {
        int cc = col0 + cb * 16 + c;
        atomicAdd(&sums[cc], s);
        atomicAdd(&sums[C_ + cc], s2);
      }
    }
  }
}

// ---------------- out-proj GEMM: sums SP bf16 partials + 1/l in A-load -----
// t0 = (sum_sp attnP / sum_sp accLp) @ outW^T + outB + h; stats -> sums.
__global__ __launch_bounds__(256) void mgemm_attn_k(const u16* __restrict__ attnP,
                                                    const float* __restrict__ accLp,
                                                    const u16* __restrict__ Bh,
                                                    const u16* __restrict__ Bl,
                                                    const float* __restrict__ bias,
                                                    float* __restrict__ Cout,
                                                    const float* __restrict__ resid,
                                                    float* __restrict__ sums) {
  constexpr int LD = 72, K = 128;
  __shared__ u16 Ah[64 * LD], Al[64 * LD], Bsh[64 * LD], Bsl[64 * LD];
  const int tid = threadIdx.x;
  const int row0 = blockIdx.y * 64, col0 = blockIdx.x * 64;
  const int wv = tid >> 6, ln = tid & 63, quad = ln >> 4, c = ln & 15;
  f32x4 acc[4];
#pragma unroll
  for (int i = 0; i < 4; ++i) acc[i] = (f32x4){0.f, 0.f, 0.f, 0.f};

  for (int kt = 0; kt < K; kt += 64) {
    const int head = kt >> 6;            // each 64-chunk is one head
    __syncthreads();
#pragma unroll
    for (int i = 0; i < 2; ++i) {
      int ch = tid + i * 256, r = ch >> 3, part = ch & 7;
      float lsum = 0.0f;
#pragma unroll
      for (int sp = 0; sp < SP_; ++sp) lsum += accLp[(sp * 2 + head) * N_ + row0 + r];
      float invl = 1.0f / lsum;
      float fv[8] = {0.f, 0.f, 0.f, 0.f, 0.f, 0.f, 0.f, 0.f};
#pragma unroll
      for (int sp = 0; sp < SP_; ++sp) {
        u16x8 pv = *(const u16x8*)&attnP[((size_t)sp * N_ + row0 + r) * C_ + kt + part * 8];
#pragma unroll
        for (int j = 0; j < 8; ++j) fv[j] += bf2f(pv[j]);
      }
      __attribute__((aligned(16))) u16 hb[8], lb[8];
#pragma unroll
      for (int j = 0; j < 8; ++j) {
        float f = fv[j] * invl;
        u16 hh = f2bf(f); hb[j] = hh; lb[j] = f2bf(f - bf2f(hh));
      }
      *(u16x8*)&Ah[r * LD + part * 8] = *(u16x8*)hb;
      *(u16x8*)&Al[r * LD + part * 8] = *(u16x8*)lb;
      size_t bo = (size_t)(col0 + r) * K + kt + part * 8;
      *(u16x8*)&Bsh[r * LD + part * 8] = *(const u16x8*)&Bh[bo];
      *(u16x8*)&Bsl[r * LD + part * 8] = *(const u16x8*)&Bl[bo];
    }
    __syncthreads();
#pragma unroll
    for (int kq = 0; kq < 2; ++kq) {
      bf16x8 ah = *(const bf16x8*)&Ah[(wv * 16 + c) * LD + kq * 32 + quad * 8];
      bf16x8 al = *(const bf16x8*)&Al[(wv * 16 + c) * LD + kq * 32 + quad * 8];
#pragma unroll
      for (int cb = 0; cb < 4; ++cb) {
        bf16x8 bh = *(const bf16x8*)&Bsh[(cb * 16 + c) * LD + kq * 32 + quad * 8];
        bf16x8 bl = *(const bf16x8*)&Bsl[(cb * 16 + c) * LD + kq * 32 + quad * 8];
        acc[cb] = __builtin_amdgcn_mfma_f32_16x16x32_bf16(al, bh, acc[cb], 0, 0, 0);
        acc[cb] = __builtin_amdgcn_mfma_f32_16x16x32_bf16(ah, bl, acc[cb], 0, 0, 0);
        acc[cb] = __builtin_amdgcn_mfma_f32_16x16x32_bf16(ah, bh, acc[cb], 0, 0, 0);
      }
    }
  }
#pragma unroll
  for (int cb = 0; cb < 4; ++cb) {
    float s = 0.0f, s2 = 0.0f;
#pragma unroll
    for (int r = 0; r < 4; ++r) {
      int rr = row0 + wv * 16 + quad * 4 + r;
      int cc = col0 + cb * 16 + c;
      float o = acc[cb][r] + bias[cc] + resid[(size_t)rr * 128 + cc];
      Cout[(size_t)rr * 128 + cc] = o;
      s += o; s2 = fmaf(o, o, s2);
    }
    s  += __shfl_xor(s, 16);  s  += __shfl_xor(s, 32);
    s2 += __shfl_xor(s2, 16); s2 += __shfl_xor(s2, 32);
    if (quad == 0) {
      int cc = col0 + cb * 16 + c;
      atomicAdd(&sums[cc], s);
      atomicAdd(&sums[C_ + cc], s2);
    }
  }
}

// ---------------- GCN aggregation: CSR gather ----------------
__global__ __launch_bounds__(128) void gcn_gather_k(const int* __restrict__ rowptr,
                                                    const int* __restrict__ csr,
                                                    const float* __restrict__ hw,
                                                    const float* __restrict__ dinv,
                                                    const float* __restrict__ b,
                                                    const float* __restrict__ hres,
                                                    float* __restrict__ out) {
  const int n = blockIdx.x, c = threadIdx.x;
  const float din = dinv[n];
  float acc = fmaf(hw[(size_t)n * C_ + c], din * din, b[c] + hres[(size_t)n * C_ + c]);
  const int e1 = rowptr[n + 1];
  for (int e = rowptr[n]; e < e1; ++e) {
    int s = csr[e];
    acc = fmaf(hw[(size_t)s * C_ + c], dinv[s] * din, acc);
  }
  out[(size_t)n * C_ + c] = acc;
}

// ---------------- BN stats (gather output) ----------------
__global__ __launch_bounds__(256) void bn_stats_k(const float* __restrict__ A,
                                                  float* __restrict__ sums) {
  int c = threadIdx.x & 127, half = threadIdx.x >> 7;
  int r0 = blockIdx.x * 16 + half * 8;
  float s = 0.0f, s2 = 0.0f;
#pragma unroll
  for (int i = 0; i < 8; ++i) {
    float v = A[(size_t)(r0 + i) * C_ + c];
    s += v;
    s2 = fmaf(v, v, s2);
  }
  __shared__ float ls[256], ls2[256];
  ls[threadIdx.x] = s; ls2[threadIdx.x] = s2;
  __syncthreads();
  if (half == 0) {
    atomicAdd(&sums[c], s + ls[c + 128]);
    atomicAdd(&sums[C_ + c], s2 + ls2[c + 128]);
  }
}

// ---------------- ob = bn1(t0) + bn0(t1) ----------------
__global__ __launch_bounds__(256) void bn_finapply2_k(const float* __restrict__ t0,
                                                      const float* __restrict__ t1,
                                                      const float* __restrict__ sums1,
                                                      const float* __restrict__ sums0,
                                                      const float* __restrict__ g1,
                                                      const float* __restrict__ b1v,
                                                      const float* __restrict__ g0,
                                                      const float* __restrict__ b0v,
                                                      float* __restrict__ ob) {
  __shared__ float scl1[128], shf1[128], scl0[128], shf0[128];
  const int t = threadIdx.x;
  if (t < 128) {
    float mu = sums1[t] * (1.0f / N_);
    float var = sums1[C_ + t] * (1.0f / N_) - mu * mu;
    float sc = rsqrtf(var + EPSV) * g1[t];
    scl1[t] = sc; shf1[t] = fmaf(-mu, sc, b1v[t]);
    mu = sums0[t] * (1.0f / N_);
    var = sums0[C_ + t] * (1.0f / N_) - mu * mu;
    sc = rsqrtf(var + EPSV) * g0[t];
    scl0[t] = sc; shf0[t] = fmaf(-mu, sc, b0v[t]);
  }
  __syncthreads();
  int idx = blockIdx.x * 256 + t;
  int c = idx & 127;
  ob[idx] = fmaf(t0[idx], scl1[c], shf1[c]) + fmaf(t1[idx], scl0[c], shf0[c]);
}

// ---------------- h = bn(A) [,relu] [,pool-atomics] ----------------
__global__ __launch_bounds__(256) void bn_finapply_k(const float* __restrict__ A,
                                                     const float* __restrict__ sums,
                                                     const float* __restrict__ g,
                                                     const float* __restrict__ b,
                                                     float* __restrict__ outp, int relu,
                                                     const int* __restrict__ batch,
                                                     float* __restrict__ pooled) {
  __shared__ float s_scl[128], s_shf[128];
  const int t = threadIdx.x;
  if (t < 128) {
    float mu = sums[t] * (1.0f / N_);
    float var = sums[C_ + t] * (1.0f / N_) - mu * mu;
    float sc = rsqrtf(var + EPSV) * g[t];
    s_scl[t] = sc;
    s_shf[t] = fmaf(-mu, sc, b[t]);
  }
  __syncthreads();
  int idx = blockIdx.x * 256 + t;
  int c = idx & 127;
  float v = fmaf(A[idx], s_scl[c], s_shf[c]);
  if (relu) v = fmaxf(v, 0.0f);
  outp[idx] = v;
  if (pooled) {
    int n = idx >> 7;
    atomicAdd(&pooled[(size_t)batch[n] * C_ + c], v);
  }
}

// ---------------- flash attention, single-bf16 MFMA, 64-q tile -------------
// grid (N/64, SP_ kv-splits, H); block 256. p = exp(s-8) (no-max, safe).
// Writes bf16 attnP[sp][q][c] and fp32 accLp[sp*2+h][q] (no atomics).
__global__ __launch_bounds__(256) void flash_mfma_k(const u16* __restrict__ Qg,
                                                    const u16* __restrict__ Kg,
                                                    const u16* __restrict__ Vtg,
                                                    u16* __restrict__ attnP,
                                                    float* __restrict__ accLp) {
  constexpr int LD = 72;
  __shared__ u16 Ks[64 * LD], Vts[64 * LD], Ps[64 * LD];
  const int tid = threadIdx.x;
  const int h = blockIdx.z, sp = blockIdx.y, q0 = blockIdx.x * 64;
  const int wv = tid >> 6, ln = tid & 63, quad = ln >> 4, c = ln & 15;
  const int KPS = N_ / SP_;              // keys per split (256)

  bf16x8 qf[2];
#pragma unroll
  for (int kq = 0; kq < 2; ++kq)
    qf[kq] = *(const bf16x8*)&Qg[((size_t)(h * N_ + q0 + wv * 16 + c)) * 64 + kq * 32 + quad * 8];

  f32x4 O[4];
#pragma unroll
  for (int i = 0; i < 4; ++i) O[i] = (f32x4){0.f, 0.f, 0.f, 0.f};
  float l4[4] = {0.f, 0.f, 0.f, 0.f};
  u16* Pw = &Ps[wv * 16 * LD];

  for (int it = 0; it < KPS / 64; ++it) {
    const int k0 = sp * KPS + it * 64;
    __syncthreads();
#pragma unroll
    for (int i = 0; i < 2; ++i) {
      int ch = tid + i * 256, row = ch >> 3, part = ch & 7;
      *(u16x8*)&Ks[row * LD + part * 8] =
          *(const u16x8*)&Kg[((size_t)(h * N_ + k0 + row)) * 64 + part * 8];
      *(u16x8*)&Vts[row * LD + part * 8] =
          *(const u16x8*)&Vtg[((size_t)(h * 64 + row)) * N_ + k0 + part * 8];
    }
    __syncthreads();

#pragma unroll
    for (int kb = 0; kb < 4; ++kb) {
      f32x4 s = (f32x4){0.f, 0.f, 0.f, 0.f};
#pragma unroll
      for (int kq = 0; kq < 2; ++kq) {
        bf16x8 b = *(const bf16x8*)&Ks[(kb * 16 + c) * LD + kq * 32 + quad * 8];
        s = __builtin_amdgcn_mfma_f32_16x16x32_bf16(qf[kq], b, s, 0, 0, 0);
      }
#pragma unroll
      for (int r = 0; r < 4; ++r) {
        u16 ph = f2bf(__expf(s[r] - 8.0f));
        l4[r] += bf2f(ph);                     // consistent with PV numerator
        Pw[(quad * 4 + r) * LD + kb * 16 + c] = ph;
      }
    }
#pragma unroll
    for (int db = 0; db < 4; ++db) {
#pragma unroll
      for (int kq = 0; kq < 2; ++kq) {
        bf16x8 a = *(const bf16x8*)&Pw[c * LD + kq * 32 + quad * 8];
        bf16x8 b = *(const bf16x8*)&Vts[(db * 16 + c) * LD + kq * 32 + quad * 8];
        O[db] = __builtin_amdgcn_mfma_f32_16x16x32_bf16(a, b, O[db], 0, 0, 0);
      }
    }
  }

#pragma unroll
  for (int r = 0; r < 4; ++r) {
#pragma unroll
    for (int off = 1; off < 16; off <<= 1) l4[r] += __shfl_xor(l4[r], off);
  }

#pragma unroll
  for (int db = 0; db < 4; ++db)
#pragma unroll
    for (int r = 0; r < 4; ++r) {
      int q = q0 + wv * 16 + quad * 4 + r;
      attnP[((size_t)sp * N_ + q) * C_ + h * 64 + db * 16 + c] = f2bf(O[db][r]);
    }
  if (c == 0) {
#pragma unroll
    for (int r = 0; r < 4; ++r)
      accLp[(sp * 2 + h) * N_ + q0 + wv * 16 + quad * 4 + r] = l4[r];
  }
}

// ---------------- final linear (cnt via binary search on sorted batch) -----
__global__ __launch_bounds__(256) void final_k(const float* __restrict__ pooled,
                                               const int* __restrict__ batch,
                                               const float* __restrict__ W,
                                               const float* __restrict__ b,
                                               float* __restrict__ out) {
  int t = threadIdx.x;
  int g = t >> 2, j = t & 3;
  int lo = 0, hi = N_;
  while (lo < hi) { int m = (lo + hi) >> 1; if (batch[m] < g) lo = m + 1; else hi = m; }
  int st = lo; lo = 0; hi = N_;
  while (lo < hi) { int m = (lo + hi) >> 1; if (batch[m] < g + 1) lo = m + 1; else hi = m; }
  float inv = 1.0f / fmaxf((float)(lo - st), 1.0f);
  float acc = b[j];
  for (int c = 0; c < C_; ++c) acc = fmaf(pooled[(size_t)g * C_ + c] * inv, W[c * 4 + j], acc);
  out[t] = acc;
}

// ---------------- host orchestration ----------------
extern "C" void kernel_launch(void* const* d_in, const int* in_sizes, int n_in,
                              void* d_out, int out_size, void* d_ws, size_t ws_size,
                              hipStream_t stream) {
  const float* x     = (const float*)d_in[0];
  const int*   ei    = (const int*)d_in[1];
  const int*   batch = (const int*)d_in[2];
  const float* projW = (const float*)d_in[3];
  const float* projB = (const float*)d_in[4];
  const float* gcnW  = (const float*)d_in[5];
  const float* gcnB  = (const float*)d_in[6];
  const float* qkvW  = (const float*)d_in[7];
  const float* qkvB  = (const float*)d_in[8];
  const float* outW  = (const float*)d_in[9];
  const float* outB  = (const float*)d_in[10];
  const float* bnG   = (const float*)d_in[11];
  const float* bnB   = (const float*)d_in[12];
  const float* w1    = (const float*)d_in[13];
  const float* b1    = (const float*)d_in[14];
  const float* w2    = (const float*)d_in[15];
  const float* b2    = (const float*)d_in[16];
  const float* linW  = (const float*)d_in[17];
  const float* linB  = (const float*)d_in[18];
  float* out = (float*)d_out;

  const size_t NC = (size_t)N_ * C_;           // 524288 floats
  const size_t HB = (size_t)2 * N_ * 64;       // 524288 u16 per head-array
  float* ws   = (float*)d_ws;
  float* h    = ws;             // NC
  float* t0   = ws + 1 * NC;    // NC
  float* t1   = ws + 2 * NC;    // NC
  float* ob   = ws + 3 * NC;    // NC
  u16* Qg  = (u16*)(ws + 4 * NC);              // 3*HB u16 within 2NC floats
  u16* Kg  = Qg + HB;
  u16* Vtg = Kg + HB;
  u16*   attnP = (u16*)(ws + 6 * NC);          // SP_*NC u16 = SP_/2 * NC floats
  float* m1b   = ws + 6 * NC + (SP_ * NC) / 2; // 2NC (disjoint from attnP)
  float* accLp = m1b + 2 * NC;                 // 2*SP_*N
  float* sums  = accLp + 2 * SP_ * N_;         // 6*256  [zero region start]
  float* pooled = sums + 6 * 256;              // G*C
  int*   icnt = (int*)(pooled + (size_t)G_ * C_); // N  [zero region end]
  float* dinv = (float*)(icnt + N_);           // N
  int*   rowptr = (int*)(dinv + N_);           // N+1
  int*   cursor = rowptr + N_ + 1;             // N
  int*   csr    = cursor + N_;                 // E
  u16*   Wh = (u16*)(csr + E_);                // 2*147456
  u16*   Wl = Wh + 2 * 147456;                 // 2*147456

  const dim3 b256(256);

  // one memset: sums(1536) + pooled(8192) + icnt(4096)
  hipMemsetAsync(sums, 0, (6 * 256 + (size_t)G_ * C_ + N_) * sizeof(float), stream);

  // CSR build (once; used by both layers)
  count_k<<<E_ / 256, b256, 0, stream>>>(ei, icnt);
  scan_k<<<1, b256, 0, stream>>>(icnt, rowptr, cursor, dinv);
  fill_k<<<E_ / 256, b256, 0, stream>>>(ei, cursor, csr);

  proj_k<<<(int)(NC / 256), b256, 0, stream>>>(x, projW, projB, h);
  wprep_k<<<288, b256, 0, stream>>>(gcnW, qkvW, outW, w1, w2, Wh, Wl);

  for (int l = 0; l < 2; ++l) {
    const size_t WL = (size_t)l * 147456;
    float* sums0 = sums + (l * 3 + 0) * 256;
    float* sums1 = sums + (l * 3 + 1) * 256;
    float* sums2 = sums + (l * 3 + 2) * 256;

    // gcn hw -> t0 ; Q/K/Vt bf16 (prep fused)
    mgemm_dual_k<<<dim3(8, 64), b256, 0, stream>>>(h, Wh + WL, Wl + WL,
                                                   qkvB + l * 384, t0, Qg, Kg, Vtg);
    // GCN branch
    gcn_gather_k<<<N_, dim3(128), 0, stream>>>(rowptr, csr, t0, dinv, gcnB + l * C_, h, t1);
    bn_stats_k<<<N_ / 16, b256, 0, stream>>>(t1, sums0);
    // attention branch
    flash_mfma_k<<<dim3(N_ / 64, SP_, 2), b256, 0, stream>>>(Qg, Kg, Vtg, attnP, accLp);
    mgemm_attn_k<<<dim3(2, 64), b256, 0, stream>>>(attnP, accLp,
                                                   Wh + WL + 65536, Wl + WL + 65536,
                                                   outB + l * C_, t0, h, sums1);
    // ob = bn1(t0) + bn0(t1)
    bn_finapply2_k<<<(int)(NC / 256), b256, 0, stream>>>(
        t0, t1, sums1, sums0,
        bnG + (l * 3 + 1) * C_, bnB + (l * 3 + 1) * C_,
        bnG + (l * 3 + 0) * C_, bnB + (l * 3 + 0) * C_, ob);
    // MLP
    mgemm_k<<<dim3(4, 64), b256, 0, stream>>>(ob, Wh + WL + 81920, Wl + WL + 81920,
                                              b1 + l * 256, m1b, 128, 256, 1,
                                              nullptr, nullptr);
    mgemm_k<<<dim3(2, 64), b256, 0, stream>>>(m1b, Wh + WL + 114688, Wl + WL + 114688,
                                              b2 + l * C_, t0, 256, 128, 0,
                                              ob, sums2);
    bn_finapply_k<<<(int)(NC / 256), b256, 0, stream>>>(
        t0, sums2, bnG + (l * 3 + 2) * C_, bnB + (l * 3 + 2) * C_, h,
        (l == 0) ? 1 : 0, batch, (l == 1) ? pooled : nullptr);
  }

  final_k<<<1, 256, 0, stream>>>(pooled, batch, linW, linB, out);
}

// Round 11
// 334.416 us; speedup vs baseline: 1.0881x; 1.0881x over previous
//
#include <hip/hip_runtime.h>
#include <hip/hip_bf16.h>

// GPS model forward. Dense GEMMs split-bf16 MFMA (~fp32 accurate); attention
// core single-bf16 MFMA (64-q tile, 8 kv-splits, fp32 partial stores). GCN via
// CSR gather. qkv prep fused into dual GEMM epilogue; out-proj GEMM merges
// kv-split partials + 1/l in A-load; BN applies merged; pooling fused.
// N=4096, IN=16, C=128, H=2 (dh=64), E=131072, G=64.
// [R11 = exact restore of the R7 optimum: 64-q/SP8/fp32-partials was best
//  (336 µs); 128-q (R8), bf16 partials (R9), SP16 (R10) all regressed.]

constexpr int N_  = 4096;
constexpr int IN_ = 16;
constexpr int C_  = 128;
constexpr int E_  = 131072;
constexpr int G_  = 64;
constexpr float EPSV = 1e-5f;
constexpr int SP_ = 8;                   // kv-splits in flash

typedef unsigned short u16;
typedef __attribute__((ext_vector_type(8))) short bf16x8;
typedef __attribute__((ext_vector_type(8))) unsigned short u16x8;
typedef __attribute__((ext_vector_type(4))) float f32x4;

__device__ inline u16 f2bf(float f) {   // HW cvt (RNE on gfx950)
  union { __hip_bfloat16 b; u16 u; } v;
  v.b = __float2bfloat16(f);
  return v.u;
}
__device__ inline float bf2f(u16 s) {
  union { unsigned u; float f; } v; v.u = ((unsigned)s) << 16;
  return v.f;
}

// ---------------- projection: h = x @ projW + projb ----------------
__global__ __launch_bounds__(256) void proj_k(const float* __restrict__ x,
                                              const float* __restrict__ W,
                                              const float* __restrict__ b,
                                              float* __restrict__ h) {
  int idx = blockIdx.x * 256 + threadIdx.x;   // N*C threads
  int n = idx >> 7, c = idx & 127;
  float acc = b[c];
#pragma unroll
  for (int k = 0; k < IN_; ++k) acc = fmaf(x[n * IN_ + k], W[k * C_ + c], acc);
  h[idx] = acc;
}

// ---------------- CSR build ----------------
__global__ __launch_bounds__(256) void count_k(const int* __restrict__ ei,
                                               int* __restrict__ cnt) {
  int e = blockIdx.x * 256 + threadIdx.x;
  atomicAdd(&cnt[ei[E_ + e]], 1);          // dst = ei[1][e]
}
__global__ __launch_bounds__(256) void scan_k(const int* __restrict__ cnt,
                                              int* __restrict__ rowptr,
                                              int* __restrict__ cursor,
                                              float* __restrict__ dinv) {
  __shared__ int part[256];
  const int t = threadIdx.x;
  int v[16], s = 0;
#pragma unroll
  for (int i = 0; i < 16; ++i) { v[i] = cnt[t * 16 + i]; s += v[i]; }
  part[t] = s;
  __syncthreads();
  if (t == 0) {
    int run = 0;
    for (int i = 0; i < 256; ++i) { int x = part[i]; part[i] = run; run += x; }
  }
  __syncthreads();
  int off = part[t];
#pragma unroll
  for (int i = 0; i < 16; ++i) {
    int n = t * 16 + i;
    rowptr[n] = off; cursor[n] = off;
    dinv[n] = rsqrtf((float)v[i] + 1.0f);  // +1 self loop
    off += v[i];
  }
  if (t == 0) rowptr[N_] = E_;
}
__global__ __launch_bounds__(256) void fill_k(const int* __restrict__ ei,
                                              int* __restrict__ cursor,
                                              int* __restrict__ csr) {
  int e = blockIdx.x * 256 + threadIdx.x;
  int d = ei[E_ + e];
  int slot = atomicAdd(&cursor[d], 1);
  csr[slot] = ei[e];                       // src
}

// ---------------- weight prep: fp32 -> split-bf16 [col][k] ----------------
// Per-layer u16 offsets: gcn@0 + qkv@16384 (contiguous 512x128), out@65536,
// w1@81920, w2@114688; layer stride 147456.
__global__ __launch_bounds__(256) void wprep_k(const float* __restrict__ gcnW,
                                               const float* __restrict__ qkvW,
                                               const float* __restrict__ outW,
                                               const float* __restrict__ w1,
                                               const float* __restrict__ w2,
                                               u16* __restrict__ Wh,
                                               u16* __restrict__ Wl) {
  int bx = blockIdx.x;                     // 288 blocks (2 layers x 144)
  int l = bx / 144, b = bx % 144;
  const float* src; int dstOff, K, M, trans;
  if (b < 16)       { src = gcnW + l * 16384; dstOff = 0;      K = 128; M = 128; trans = 0; }
  else if (b < 64)  { src = qkvW + l * 49152; dstOff = 16384;  K = 128; M = 0;   trans = 1; b -= 16; }
  else if (b < 80)  { src = outW + l * 16384; dstOff = 65536;  K = 128; M = 0;   trans = 1; b -= 64; }
  else if (b < 112) { src = w1 + l * 32768;   dstOff = 81920;  K = 128; M = 256; trans = 0; b -= 80; }
  else              { src = w2 + l * 32768;   dstOff = 114688; K = 256; M = 128; trans = 0; b -= 112; }
  dstOff += l * 147456;
  int d = b * 1024 + threadIdx.x * 4;
  float v[4];
  if (trans) {
    const float4 f = *(const float4*)&src[d];
    v[0] = f.x; v[1] = f.y; v[2] = f.z; v[3] = f.w;
  } else {
    int ks = (K == 256) ? 8 : 7;
    int n = d >> ks, k = d & (K - 1);
#pragma unroll
    for (int j = 0; j < 4; ++j) v[j] = src[(size_t)(k + j) * M + n];
  }
  ushort4 hv, lv;
  u16* hp = (u16*)&hv; u16* lp = (u16*)&lv;
#pragma unroll
  for (int j = 0; j < 4; ++j) {
    u16 hh = f2bf(v[j]); hp[j] = hh; lp[j] = f2bf(v[j] - bf2f(hh));
  }
  *(ushort4*)&Wh[dstOff + d] = hv;
  *(ushort4*)&Wl[dstOff + d] = lv;
}

// ---------------- dual GEMM + qkv prep epilogue ----------------
// grid (8, 64). Col-blocks: 0-1 -> t0 (gcn hw, fp32); 2-3 -> Qg bf16 (scaled,
// +bias); 4-5 -> Kg bf16 (+bias); 6-7 -> Vtg bf16 transposed (+bias).
__global__ __launch_bounds__(256) void mgemm_dual_k(const float* __restrict__ A,
                                                    const u16* __restrict__ Bh,
                                                    const u16* __restrict__ Bl,
                                                    const float* __restrict__ qkvB,
                                                    float* __restrict__ t0,
                                                    u16* __restrict__ Qg,
                                                    u16* __restrict__ Kg,
                                                    u16* __restrict__ Vtg) {
  constexpr int LD = 72, K = 128;
  __shared__ u16 Ah[64 * LD], Al[64 * LD], Bsh[64 * LD], Bsl[64 * LD];
  const int tid = threadIdx.x;
  const int row0 = blockIdx.y * 64, col0 = blockIdx.x * 64;
  const int wv = tid >> 6, ln = tid & 63, quad = ln >> 4, c = ln & 15;
  f32x4 acc[4];
#pragma unroll
  for (int i = 0; i < 4; ++i) acc[i] = (f32x4){0.f, 0.f, 0.f, 0.f};

  for (int kt = 0; kt < K; kt += 64) {
    __syncthreads();
#pragma unroll
    for (int i = 0; i < 2; ++i) {
      int ch = tid + i * 256, r = ch >> 3, part = ch & 7;
      const float4 f0 = *(const float4*)&A[(size_t)(row0 + r) * K + kt + part * 8];
      const float4 f1 = *(const float4*)&A[(size_t)(row0 + r) * K + kt + part * 8 + 4];
      float fv[8] = {f0.x, f0.y, f0.z, f0.w, f1.x, f1.y, f1.z, f1.w};
      __attribute__((aligned(16))) u16 hb[8], lb[8];
#pragma unroll
      for (int j = 0; j < 8; ++j) {
        u16 hh = f2bf(fv[j]); hb[j] = hh; lb[j] = f2bf(fv[j] - bf2f(hh));
      }
      *(u16x8*)&Ah[r * LD + part * 8] = *(u16x8*)hb;
      *(u16x8*)&Al[r * LD + part * 8] = *(u16x8*)lb;
      size_t bo = (size_t)(col0 + r) * K + kt + part * 8;
      *(u16x8*)&Bsh[r * LD + part * 8] = *(const u16x8*)&Bh[bo];
      *(u16x8*)&Bsl[r * LD + part * 8] = *(const u16x8*)&Bl[bo];
    }
    __syncthreads();
#pragma unroll
    for (int kq = 0; kq < 2; ++kq) {
      bf16x8 ah = *(const bf16x8*)&Ah[(wv * 16 + c) * LD + kq * 32 + quad * 8];
      bf16x8 al = *(const bf16x8*)&Al[(wv * 16 + c) * LD + kq * 32 + quad * 8];
#pragma unroll
      for (int cb = 0; cb < 4; ++cb) {
        bf16x8 bh = *(const bf16x8*)&Bsh[(cb * 16 + c) * LD + kq * 32 + quad * 8];
        bf16x8 bl = *(const bf16x8*)&Bsl[(cb * 16 + c) * LD + kq * 32 + quad * 8];
        acc[cb] = __builtin_amdgcn_mfma_f32_16x16x32_bf16(al, bh, acc[cb], 0, 0, 0);
        acc[cb] = __builtin_amdgcn_mfma_f32_16x16x32_bf16(ah, bl, acc[cb], 0, 0, 0);
        acc[cb] = __builtin_amdgcn_mfma_f32_16x16x32_bf16(ah, bh, acc[cb], 0, 0, 0);
      }
    }
  }

  const int cls = blockIdx.x;            // block-uniform
  if (cls < 2) {                         // gcn hw -> t0, fp32, no bias
#pragma unroll
    for (int cb = 0; cb < 4; ++cb)
#pragma unroll
      for (int r = 0; r < 4; ++r) {
        int rr = row0 + wv * 16 + quad * 4 + r;
        t0[(size_t)rr * 128 + col0 + cb * 16 + c] = acc[cb][r];
      }
  } else if (cls < 6) {                  // Q or K -> bf16 [h][n][64]
    const int isQ = cls < 4, h = cls & 1;
    const float sc = isQ ? 0.125f : 1.0f;
    u16* dst = isQ ? Qg : Kg;
#pragma unroll
    for (int cb = 0; cb < 4; ++cb) {
      int d = cb * 16 + c;
      float qb = qkvB[col0 - 128 + d];
#pragma unroll
      for (int r = 0; r < 4; ++r) {
        int rr = row0 + wv * 16 + quad * 4 + r;
        dst[((size_t)(h * N_ + rr)) * 64 + d] = f2bf((acc[cb][r] + qb) * sc);
      }
    }
  } else {                               // V -> bf16 transposed [h][64][n]
    const int h = cls & 1;
    u16* vtile = Ah;                     // reuse (64 x 72)
    __syncthreads();                     // all MFMA LDS reads done
#pragma unroll
    for (int cb = 0; cb < 4; ++cb) {
      int d = cb * 16 + c;
      float vb = qkvB[col0 - 128 + d];
#pragma unroll
      for (int r = 0; r < 4; ++r)
        vtile[(wv * 16 + quad * 4 + r) * LD + d] = f2bf(acc[cb][r] + vb);
    }
    __syncthreads();
    int d = tid >> 2, j = tid & 3;
    __attribute__((aligned(16))) u16 buf[16];
#pragma unroll
    for (int m = 0; m < 16; ++m) buf[m] = vtile[(j * 16 + m) * LD + d];
    size_t o = ((size_t)(h * 64 + d)) * N_ + row0 + j * 16;
    *(u16x8*)&Vtg[o]     = *(u16x8*)&buf[0];
    *(u16x8*)&Vtg[o + 8] = *(u16x8*)&buf[8];
  }
}

// ---------------- generic MFMA GEMM with fused epilogue ----------------
// C = A @ B^T + bias [+resid] [,relu]; optional column stats into sums.
__global__ __launch_bounds__(256) void mgemm_k(const float* __restrict__ A,
                                               const u16* __restrict__ Bh,
                                               const u16* __restrict__ Bl,
                                               const float* __restrict__ bias,
                                               float* __restrict__ Cout,
                                               int K, int Ncols, int relu,
                                               const float* __restrict__ resid,
                                               float* __restrict__ sums) {
  constexpr int LD = 72;
  __shared__ u16 Ah[64 * LD], Al[64 * LD], Bsh[64 * LD], Bsl[64 * LD];
  const int tid = threadIdx.x;
  const int row0 = blockIdx.y * 64, col0 = blockIdx.x * 64;
  const int wv = tid >> 6, ln = tid & 63, quad = ln >> 4, c = ln & 15;
  f32x4 acc[4];
#pragma unroll
  for (int i = 0; i < 4; ++i) acc[i] = (f32x4){0.f, 0.f, 0.f, 0.f};

  for (int kt = 0; kt < K; kt += 64) {
    __syncthreads();
#pragma unroll
    for (int i = 0; i < 2; ++i) {
      int ch = tid + i * 256, r = ch >> 3, part = ch & 7;
      const float4 f0 = *(const float4*)&A[(size_t)(row0 + r) * K + kt + part * 8];
      const float4 f1 = *(const float4*)&A[(size_t)(row0 + r) * K + kt + part * 8 + 4];
      float fv[8] = {f0.x, f0.y, f0.z, f0.w, f1.x, f1.y, f1.z, f1.w};
      __attribute__((aligned(16))) u16 hb[8], lb[8];
#pragma unroll
      for (int j = 0; j < 8; ++j) {
        u16 hh = f2bf(fv[j]); hb[j] = hh; lb[j] = f2bf(fv[j] - bf2f(hh));
      }
      *(u16x8*)&Ah[r * LD + part * 8] = *(u16x8*)hb;
      *(u16x8*)&Al[r * LD + part * 8] = *(u16x8*)lb;
      size_t bo = (size_t)(col0 + r) * K + kt + part * 8;
      *(u16x8*)&Bsh[r * LD + part * 8] = *(const u16x8*)&Bh[bo];
      *(u16x8*)&Bsl[r * LD + part * 8] = *(const u16x8*)&Bl[bo];
    }
    __syncthreads();
#pragma unroll
    for (int kq = 0; kq < 2; ++kq) {
      bf16x8 ah = *(const bf16x8*)&Ah[(wv * 16 + c) * LD + kq * 32 + quad * 8];
      bf16x8 al = *(const bf16x8*)&Al[(wv * 16 + c) * LD + kq * 32 + quad * 8];
#pragma unroll
      for (int cb = 0; cb < 4; ++cb) {
        bf16x8 bh = *(const bf16x8*)&Bsh[(cb * 16 + c) * LD + kq * 32 + quad * 8];
        bf16x8 bl = *(const bf16x8*)&Bsl[(cb * 16 + c) * LD + kq * 32 + quad * 8];
        acc[cb] = __builtin_amdgcn_mfma_f32_16x16x32_bf16(al, bh, acc[cb], 0, 0, 0);
        acc[cb] = __builtin_amdgcn_mfma_f32_16x16x32_bf16(ah, bl, acc[cb], 0, 0, 0);
        acc[cb] = __builtin_amdgcn_mfma_f32_16x16x32_bf16(ah, bh, acc[cb], 0, 0, 0);
      }
    }
  }
#pragma unroll
  for (int cb = 0; cb < 4; ++cb) {
    float s = 0.0f, s2 = 0.0f;
#pragma unroll
    for (int r = 0; r < 4; ++r) {
      int rr = row0 + wv * 16 + quad * 4 + r;
      int cc = col0 + cb * 16 + c;
      float o = acc[cb][r] + (bias ? bias[cc] : 0.0f);
      if (resid) o += resid[(size_t)rr * Ncols + cc];
      if (relu) o = fmaxf(o, 0.0f);
      Cout[(size_t)rr * Ncols + cc] = o;
      s += o; s2 = fmaf(o, o, s2);
    }
    if (sums) {
      s  += __shfl_xor(s, 16);  s  += __shfl_xor(s, 32);
      s2 += __shfl_xor(s2, 16); s2 += __shfl_xor(s2, 32);
      if (quad == 0) {
        int cc = col0 + cb * 16 + c;
        atomicAdd(&sums[cc], s);
        atomicAdd(&sums[C_ + cc], s2);
      }
    }
  }
}

// ---------------- out-proj GEMM: sums SP kv-split partials + 1/l in A-load --
// t0 = (sum_sp attnP / sum_sp accLp) @ outW^T + outB + h; stats -> sums.
__global__ __launch_bounds__(256) void mgemm_attn_k(const float* __restrict__ attnP,
                                                    const float* __restrict__ accLp,
                                                    const u16* __restrict__ Bh,
                                                    const u16* __restrict__ Bl,
                                                    const float* __restrict__ bias,
                                                    float* __restrict__ Cout,
                                                    const float* __restrict__ resid,
                                                    float* __restrict__ sums) {
  constexpr int LD = 72, K = 128;
  __shared__ u16 Ah[64 * LD], Al[64 * LD], Bsh[64 * LD], Bsl[64 * LD];
  const int tid = threadIdx.x;
  const int row0 = blockIdx.y * 64, col0 = blockIdx.x * 64;
  const int wv = tid >> 6, ln = tid & 63, quad = ln >> 4, c = ln & 15;
  f32x4 acc[4];
#pragma unroll
  for (int i = 0; i < 4; ++i) acc[i] = (f32x4){0.f, 0.f, 0.f, 0.f};

  for (int kt = 0; kt < K; kt += 64) {
    const int head = kt >> 6;            // each 64-chunk is one head
    __syncthreads();
#pragma unroll
    for (int i = 0; i < 2; ++i) {
      int ch = tid + i * 256, r = ch >> 3, part = ch & 7;
      float lsum = 0.0f;
#pragma unroll
      for (int sp = 0; sp < SP_; ++sp) lsum += accLp[(sp * 2 + head) * N_ + row0 + r];
      float invl = 1.0f / lsum;
      float fv[8] = {0.f, 0.f, 0.f, 0.f, 0.f, 0.f, 0.f, 0.f};
#pragma unroll
      for (int sp = 0; sp < SP_; ++sp) {
        const float* p = &attnP[((size_t)sp * N_ + row0 + r) * C_ + kt + part * 8];
        const float4 f0 = *(const float4*)p;
        const float4 f1 = *(const float4*)(p + 4);
        fv[0] += f0.x; fv[1] += f0.y; fv[2] += f0.z; fv[3] += f0.w;
        fv[4] += f1.x; fv[5] += f1.y; fv[6] += f1.z; fv[7] += f1.w;
      }
      __attribute__((aligned(16))) u16 hb[8], lb[8];
#pragma unroll
      for (int j = 0; j < 8; ++j) {
        float f = fv[j] * invl;
        u16 hh = f2bf(f); hb[j] = hh; lb[j] = f2bf(f - bf2f(hh));
      }
      *(u16x8*)&Ah[r * LD + part * 8] = *(u16x8*)hb;
      *(u16x8*)&Al[r * LD + part * 8] = *(u16x8*)lb;
      size_t bo = (size_t)(col0 + r) * K + kt + part * 8;
      *(u16x8*)&Bsh[r * LD + part * 8] = *(const u16x8*)&Bh[bo];
      *(u16x8*)&Bsl[r * LD + part * 8] = *(const u16x8*)&Bl[bo];
    }
    __syncthreads();
#pragma unroll
    for (int kq = 0; kq < 2; ++kq) {
      bf16x8 ah = *(const bf16x8*)&Ah[(wv * 16 + c) * LD + kq * 32 + quad * 8];
      bf16x8 al = *(const bf16x8*)&Al[(wv * 16 + c) * LD + kq * 32 + quad * 8];
#pragma unroll
      for (int cb = 0; cb < 4; ++cb) {
        bf16x8 bh = *(const bf16x8*)&Bsh[(cb * 16 + c) * LD + kq * 32 + quad * 8];
        bf16x8 bl = *(const bf16x8*)&Bsl[(cb * 16 + c) * LD + kq * 32 + quad * 8];
        acc[cb] = __builtin_amdgcn_mfma_f32_16x16x32_bf16(al, bh, acc[cb], 0, 0, 0);
        acc[cb] = __builtin_amdgcn_mfma_f32_16x16x32_bf16(ah, bl, acc[cb], 0, 0, 0);
        acc[cb] = __builtin_amdgcn_mfma_f32_16x16x32_bf16(ah, bh, acc[cb], 0, 0, 0);
      }
    }
  }
#pragma unroll
  for (int cb = 0; cb < 4; ++cb) {
    float s = 0.0f, s2 = 0.0f;
#pragma unroll
    for (int r = 0; r < 4; ++r) {
      int rr = row0 + wv * 16 + quad * 4 + r;
      int cc = col0 + cb * 16 + c;
      float o = acc[cb][r] + bias[cc] + resid[(size_t)rr * 128 + cc];
      Cout[(size_t)rr * 128 + cc] = o;
      s += o; s2 = fmaf(o, o, s2);
    }
    s  += __shfl_xor(s, 16);  s  += __shfl_xor(s, 32);
    s2 += __shfl_xor(s2, 16); s2 += __shfl_xor(s2, 32);
    if (quad == 0) {
      int cc = col0 + cb * 16 + c;
      atomicAdd(&sums[cc], s);
      atomicAdd(&sums[C_ + cc], s2);
    }
  }
}

// ---------------- GCN aggregation: CSR gather ----------------
__global__ __launch_bounds__(128) void gcn_gather_k(const int* __restrict__ rowptr,
                                                    const int* __restrict__ csr,
                                                    const float* __restrict__ hw,
                                                    const float* __restrict__ dinv,
                                                    const float* __restrict__ b,
                                                    const float* __restrict__ hres,
                                                    float* __restrict__ out) {
  const int n = blockIdx.x, c = threadIdx.x;
  const float din = dinv[n];
  float acc = fmaf(hw[(size_t)n * C_ + c], din * din, b[c] + hres[(size_t)n * C_ + c]);
  const int e1 = rowptr[n + 1];
  for (int e = rowptr[n]; e < e1; ++e) {
    int s = csr[e];
    acc = fmaf(hw[(size_t)s * C_ + c], dinv[s] * din, acc);
  }
  out[(size_t)n * C_ + c] = acc;
}

// ---------------- BN stats (gather output) ----------------
__global__ __launch_bounds__(256) void bn_stats_k(const float* __restrict__ A,
                                                  float* __restrict__ sums) {
  int c = threadIdx.x & 127, half = threadIdx.x >> 7;
  int r0 = blockIdx.x * 16 + half * 8;
  float s = 0.0f, s2 = 0.0f;
#pragma unroll
  for (int i = 0; i < 8; ++i) {
    float v = A[(size_t)(r0 + i) * C_ + c];
    s += v;
    s2 = fmaf(v, v, s2);
  }
  __shared__ float ls[256], ls2[256];
  ls[threadIdx.x] = s; ls2[threadIdx.x] = s2;
  __syncthreads();
  if (half == 0) {
    atomicAdd(&sums[c], s + ls[c + 128]);
    atomicAdd(&sums[C_ + c], s2 + ls2[c + 128]);
  }
}

// ---------------- ob = bn1(t0) + bn0(t1) ----------------
__global__ __launch_bounds__(256) void bn_finapply2_k(const float* __restrict__ t0,
                                                      const float* __restrict__ t1,
                                                      const float* __restrict__ sums1,
                                                      const float* __restrict__ sums0,
                                                      const float* __restrict__ g1,
                                                      const float* __restrict__ b1v,
                                                      const float* __restrict__ g0,
                                                      const float* __restrict__ b0v,
                                                      float* __restrict__ ob) {
  __shared__ float scl1[128], shf1[128], scl0[128], shf0[128];
  const int t = threadIdx.x;
  if (t < 128) {
    float mu = sums1[t] * (1.0f / N_);
    float var = sums1[C_ + t] * (1.0f / N_) - mu * mu;
    float sc = rsqrtf(var + EPSV) * g1[t];
    scl1[t] = sc; shf1[t] = fmaf(-mu, sc, b1v[t]);
    mu = sums0[t] * (1.0f / N_);
    var = sums0[C_ + t] * (1.0f / N_) - mu * mu;
    sc = rsqrtf(var + EPSV) * g0[t];
    scl0[t] = sc; shf0[t] = fmaf(-mu, sc, b0v[t]);
  }
  __syncthreads();
  int idx = blockIdx.x * 256 + t;
  int c = idx & 127;
  ob[idx] = fmaf(t0[idx], scl1[c], shf1[c]) + fmaf(t1[idx], scl0[c], shf0[c]);
}

// ---------------- h = bn(A) [,relu] [,pool-atomics] ----------------
__global__ __launch_bounds__(256) void bn_finapply_k(const float* __restrict__ A,
                                                     const float* __restrict__ sums,
                                                     const float* __restrict__ g,
                                                     const float* __restrict__ b,
                                                     float* __restrict__ outp, int relu,
                                                     const int* __restrict__ batch,
                                                     float* __restrict__ pooled) {
  __shared__ float s_scl[128], s_shf[128];
  const int t = threadIdx.x;
  if (t < 128) {
    float mu = sums[t] * (1.0f / N_);
    float var = sums[C_ + t] * (1.0f / N_) - mu * mu;
    float sc = rsqrtf(var + EPSV) * g[t];
    s_scl[t] = sc;
    s_shf[t] = fmaf(-mu, sc, b[t]);
  }
  __syncthreads();
  int idx = blockIdx.x * 256 + t;
  int c = idx & 127;
  float v = fmaf(A[idx], s_scl[c], s_shf[c]);
  if (relu) v = fmaxf(v, 0.0f);
  outp[idx] = v;
  if (pooled) {
    int n = idx >> 7;
    atomicAdd(&pooled[(size_t)batch[n] * C_ + c], v);
  }
}

// ---------------- flash attention, single-bf16 MFMA, 64-q tile -------------
// grid (N/64, SP_ kv-splits, H); block 256. p = exp(s-8) (no-max, safe).
// Writes fp32 attnP[sp][q][c] and accLp[sp*2+h][q] (no atomics).
__global__ __launch_bounds__(256) void flash_mfma_k(const u16* __restrict__ Qg,
                                                    const u16* __restrict__ Kg,
                                                    const u16* __restrict__ Vtg,
                                                    float* __restrict__ attnP,
                                                    float* __restrict__ accLp) {
  constexpr int LD = 72;
  __shared__ u16 Ks[64 * LD], Vts[64 * LD], Ps[64 * LD];
  const int tid = threadIdx.x;
  const int h = blockIdx.z, sp = blockIdx.y, q0 = blockIdx.x * 64;
  const int wv = tid >> 6, ln = tid & 63, quad = ln >> 4, c = ln & 15;
  const int KPS = N_ / SP_;              // keys per split (512)

  bf16x8 qf[2];
#pragma unroll
  for (int kq = 0; kq < 2; ++kq)
    qf[kq] = *(const bf16x8*)&Qg[((size_t)(h * N_ + q0 + wv * 16 + c)) * 64 + kq * 32 + quad * 8];

  f32x4 O[4];
#pragma unroll
  for (int i = 0; i < 4; ++i) O[i] = (f32x4){0.f, 0.f, 0.f, 0.f};
  float l4[4] = {0.f, 0.f, 0.f, 0.f};
  u16* Pw = &Ps[wv * 16 * LD];

  for (int it = 0; it < KPS / 64; ++it) {
    const int k0 = sp * KPS + it * 64;
    __syncthreads();
#pragma unroll
    for (int i = 0; i < 2; ++i) {
      int ch = tid + i * 256, row = ch >> 3, part = ch & 7;
      *(u16x8*)&Ks[row * LD + part * 8] =
          *(const u16x8*)&Kg[((size_t)(h * N_ + k0 + row)) * 64 + part * 8];
      *(u16x8*)&Vts[row * LD + part * 8] =
          *(const u16x8*)&Vtg[((size_t)(h * 64 + row)) * N_ + k0 + part * 8];
    }
    __syncthreads();

#pragma unroll
    for (int kb = 0; kb < 4; ++kb) {
      f32x4 s = (f32x4){0.f, 0.f, 0.f, 0.f};
#pragma unroll
      for (int kq = 0; kq < 2; ++kq) {
        bf16x8 b = *(const bf16x8*)&Ks[(kb * 16 + c) * LD + kq * 32 + quad * 8];
        s = __builtin_amdgcn_mfma_f32_16x16x32_bf16(qf[kq], b, s, 0, 0, 0);
      }
#pragma unroll
      for (int r = 0; r < 4; ++r) {
        u16 ph = f2bf(__expf(s[r] - 8.0f));
        l4[r] += bf2f(ph);                     // consistent with PV numerator
        Pw[(quad * 4 + r) * LD + kb * 16 + c] = ph;
      }
    }
#pragma unroll
    for (int db = 0; db < 4; ++db) {
#pragma unroll
      for (int kq = 0; kq < 2; ++kq) {
        bf16x8 a = *(const bf16x8*)&Pw[c * LD + kq * 32 + quad * 8];
        bf16x8 b = *(const bf16x8*)&Vts[(db * 16 + c) * LD + kq * 32 + quad * 8];
        O[db] = __builtin_amdgcn_mfma_f32_16x16x32_bf16(a, b, O[db], 0, 0, 0);
      }
    }
  }

#pragma unroll
  for (int r = 0; r < 4; ++r) {
#pragma unroll
    for (int off = 1; off < 16; off <<= 1) l4[r] += __shfl_xor(l4[r], off);
  }

#pragma unroll
  for (int db = 0; db < 4; ++db)
#pragma unroll
    for (int r = 0; r < 4; ++r) {
      int q = q0 + wv * 16 + quad * 4 + r;
      attnP[((size_t)sp * N_ + q) * C_ + h * 64 + db * 16 + c] = O[db][r];
    }
  if (c == 0) {
#pragma unroll
    for (int r = 0; r < 4; ++r)
      accLp[(sp * 2 + h) * N_ + q0 + wv * 16 + quad * 4 + r] = l4[r];
  }
}

// ---------------- final linear (cnt via binary search on sorted batch) -----
__global__ __launch_bounds__(256) void final_k(const float* __restrict__ pooled,
                                               const int* __restrict__ batch,
                                               const float* __restrict__ W,
                                               const float* __restrict__ b,
                                               float* __restrict__ out) {
  int t = threadIdx.x;
  int g = t >> 2, j = t & 3;
  int lo = 0, hi = N_;
  while (lo < hi) { int m = (lo + hi) >> 1; if (batch[m] < g) lo = m + 1; else hi = m; }
  int st = lo; lo = 0; hi = N_;
  while (lo < hi) { int m = (lo + hi) >> 1; if (batch[m] < g + 1) lo = m + 1; else hi = m; }
  float inv = 1.0f / fmaxf((float)(lo - st), 1.0f);
  float acc = b[j];
  for (int c = 0; c < C_; ++c) acc = fmaf(pooled[(size_t)g * C_ + c] * inv, W[c * 4 + j], acc);
  out[t] = acc;
}

// ---------------- host orchestration ----------------
extern "C" void kernel_launch(void* const* d_in, const int* in_sizes, int n_in,
                              void* d_out, int out_size, void* d_ws, size_t ws_size,
                              hipStream_t stream) {
  const float* x     = (const float*)d_in[0];
  const int*   ei    = (const int*)d_in[1];
  const int*   batch = (const int*)d_in[2];
  const float* projW = (const float*)d_in[3];
  const float* projB = (const float*)d_in[4];
  const float* gcnW  = (const float*)d_in[5];
  const float* gcnB  = (const float*)d_in[6];
  const float* qkvW  = (const float*)d_in[7];
  const float* qkvB  = (const float*)d_in[8];
  const float* outW  = (const float*)d_in[9];
  const float* outB  = (const float*)d_in[10];
  const float* bnG   = (const float*)d_in[11];
  const float* bnB   = (const float*)d_in[12];
  const float* w1    = (const float*)d_in[13];
  const float* b1    = (const float*)d_in[14];
  const float* w2    = (const float*)d_in[15];
  const float* b2    = (const float*)d_in[16];
  const float* linW  = (const float*)d_in[17];
  const float* linB  = (const float*)d_in[18];
  float* out = (float*)d_out;

  const size_t NC = (size_t)N_ * C_;           // 524288 floats
  const size_t HB = (size_t)2 * N_ * 64;       // 524288 u16 per head-array
  float* ws   = (float*)d_ws;
  float* h    = ws;             // NC
  float* t0   = ws + 1 * NC;    // NC
  float* t1   = ws + 2 * NC;    // NC
  float* ob   = ws + 3 * NC;    // NC
  u16* Qg  = (u16*)(ws + 4 * NC);              // 3*HB u16 within 2NC floats
  u16* Kg  = Qg + HB;
  u16* Vtg = Kg + HB;
  float* attnP = ws + 6 * NC;                  // SP_*NC (overwritten each layer)
  float* m1b   = attnP;                        // 2NC overlay (safe: after attn)
  float* accLp = ws + (6 + SP_) * NC;          // 2*SP_*N
  float* sums  = accLp + 2 * SP_ * N_;         // 6*256  [zero region start]
  float* pooled = sums + 6 * 256;              // G*C
  int*   icnt = (int*)(pooled + (size_t)G_ * C_); // N  [zero region end]
  float* dinv = (float*)(icnt + N_);           // N
  int*   rowptr = (int*)(dinv + N_);           // N+1
  int*   cursor = rowptr + N_ + 1;             // N
  int*   csr    = cursor + N_;                 // E
  u16*   Wh = (u16*)(csr + E_);                // 2*147456
  u16*   Wl = Wh + 2 * 147456;                 // 2*147456

  const dim3 b256(256);

  // one memset: sums(1536) + pooled(8192) + icnt(4096)
  hipMemsetAsync(sums, 0, (6 * 256 + (size_t)G_ * C_ + N_) * sizeof(float), stream);

  // CSR build (once; used by both layers)
  count_k<<<E_ / 256, b256, 0, stream>>>(ei, icnt);
  scan_k<<<1, b256, 0, stream>>>(icnt, rowptr, cursor, dinv);
  fill_k<<<E_ / 256, b256, 0, stream>>>(ei, cursor, csr);

  proj_k<<<(int)(NC / 256), b256, 0, stream>>>(x, projW, projB, h);
  wprep_k<<<288, b256, 0, stream>>>(gcnW, qkvW, outW, w1, w2, Wh, Wl);

  for (int l = 0; l < 2; ++l) {
    const size_t WL = (size_t)l * 147456;
    float* sums0 = sums + (l * 3 + 0) * 256;
    float* sums1 = sums + (l * 3 + 1) * 256;
    float* sums2 = sums + (l * 3 + 2) * 256;

    // gcn hw -> t0 ; Q/K/Vt bf16 (prep fused)
    mgemm_dual_k<<<dim3(8, 64), b256, 0, stream>>>(h, Wh + WL, Wl + WL,
                                                   qkvB + l * 384, t0, Qg, Kg, Vtg);
    // GCN branch
    gcn_gather_k<<<N_, dim3(128), 0, stream>>>(rowptr, csr, t0, dinv, gcnB + l * C_, h, t1);
    bn_stats_k<<<N_ / 16, b256, 0, stream>>>(t1, sums0);
    // attention branch
    flash_mfma_k<<<dim3(N_ / 64, SP_, 2), b256, 0, stream>>>(Qg, Kg, Vtg, attnP, accLp);
    mgemm_attn_k<<<dim3(2, 64), b256, 0, stream>>>(attnP, accLp,
                                                   Wh + WL + 65536, Wl + WL + 65536,
                                                   outB + l * C_, t0, h, sums1);
    // ob = bn1(t0) + bn0(t1)
    bn_finapply2_k<<<(int)(NC / 256), b256, 0, stream>>>(
        t0, t1, sums1, sums0,
        bnG + (l * 3 + 1) * C_, bnB + (l * 3 + 1) * C_,
        bnG + (l * 3 + 0) * C_, bnB + (l * 3 + 0) * C_, ob);
    // MLP
    mgemm_k<<<dim3(4, 64), b256, 0, stream>>>(ob, Wh + WL + 81920, Wl + WL + 81920,
                                              b1 + l * 256, m1b, 128, 256, 1,
                                              nullptr, nullptr);
    mgemm_k<<<dim3(2, 64), b256, 0, stream>>>(m1b, Wh + WL + 114688, Wl + WL + 114688,
                                              b2 + l * C_, t0, 256, 128, 0,
                                              ob, sums2);
    bn_finapply_k<<<(int)(NC / 256), b256, 0, stream>>>(
        t0, sums2, bnG + (l * 3 + 2) * C_, bnB + (l * 3 + 2) * C_, h,
        (l == 0) ? 1 : 0, batch, (l == 1) ? pooled : nullptr);
  }

  final_k<<<1, 256, 0, stream>>>(pooled, batch, linW, linB, out);
}